// Round 21
// baseline (1301.193 us; speedup 1.0000x reference)
//
#include <hip/hip_runtime.h>
#include <hip/hip_bf16.h>
#include <math.h>

#define NN 20000
#define NE 160000
#define NG 256
#define EPSV 1e-5f
#define NQB 2500   // edge-groups of 64

typedef short bf16x8 __attribute__((ext_vector_type(8)));
typedef unsigned short u16x8 __attribute__((ext_vector_type(8)));
typedef float f32x4 __attribute__((ext_vector_type(4)));

__device__ __forceinline__ unsigned short f2bf(float f){
  unsigned int u = __float_as_uint(f);
  unsigned int r = (u + 0x7fffu + ((u>>16)&1u)) >> 16;
  return (unsigned short)r;
}
__device__ __forceinline__ float bf2f(unsigned short h){
  return __uint_as_float(((unsigned int)h) << 16);
}
__device__ __forceinline__ float fastmsg(float f, float sv){
  float sg = __builtin_amdgcn_rcpf(1.0f + __expf(-f));
  float sp = fmaxf(sv, 0.0f) + __logf(1.0f + __expf(-fabsf(sv)));
  return sg * sp;
}

// ---- one-time: dst-sort of edges (counting sort) ----
__global__ __launch_bounds__(256) void k_hist(const int* __restrict__ ei, int* __restrict__ deg){
  int e = blockIdx.x*256 + threadIdx.x;
  if (e < NE) atomicAdd(&deg[ei[NE+e]], 1);
}
__global__ __launch_bounds__(1024) void k_scan(const int* __restrict__ deg,
                                               int* __restrict__ start, int* __restrict__ cur){
  __shared__ int part[1024];
  int t = threadIdx.x;
  int base = t*20;
  int s = 0;
  for (int j=0;j<20;j++){ int i = base+j; if (i<NN) s += deg[i]; }
  part[t] = s; __syncthreads();
  for (int off=1; off<1024; off<<=1){
    int v = (t >= off) ? part[t-off] : 0;
    __syncthreads();
    part[t] += v;
    __syncthreads();
  }
  int run = (t>0) ? part[t-1] : 0;
  for (int j=0;j<20;j++){
    int i = base+j;
    if (i<NN){ start[i] = run; cur[i] = run; run += deg[i]; }
  }
}
__global__ __launch_bounds__(256) void k_scatter(
    const int* __restrict__ ei, const float* __restrict__ eattr,
    int* __restrict__ cur, int2* __restrict__ esd, float* __restrict__ ea_s){
  int e = blockIdx.x*256 + threadIdx.x;
  if (e >= NE) return;
  int d = ei[NE+e];
  int p = atomicAdd(&cur[d], 1);
  esd[p] = make_int2(ei[e], d);
  ea_s[p*3+0] = eattr[e*3+0];
  ea_s[p*3+1] = eattr[e*3+1];
  ea_s[p*3+2] = eattr[e*3+2];
}

// ---- one-time: pack ALL weight blocks into MFMA B-frag layout, 3-term bf16 split.
// matrix id m = (L*2+g)*3 + blk  (g: 0=f,1=s; blk: 0=dst,1=src,2=e)
// frag (nt,ks): lane l takes B[k=ks*32+(l>>4)*8+j][col=nt*16+(l&15)]
__global__ __launch_bounds__(256) void k_pack_w(
    const float* __restrict__ Wf, const float* __restrict__ Ws,
    unsigned short* __restrict__ Wpk_hi, unsigned short* __restrict__ Wpk_md,
    unsigned short* __restrict__ Wpk_lo)
{
  int idx = blockIdx.x*256 + threadIdx.x;   // 60 * 2048 = 122880
  if (idx >= 122880) return;
  int l = idx & 63, ks = (idx>>6)&3, nt = (idx>>8)&7;
  int m = idx >> 11;            // 0..59
  int blk = m % 3, gL = m / 3;
  int g = gL & 1, L = gL >> 1;
  const float* src = (g ? Ws : Wf) + (size_t)L*384*128;
  size_t off = (size_t)m*16384 + (nt*4+ks)*512 + l*8;
  int col = nt*16 + (l&15), k0 = ks*32 + (l>>4)*8;
  #pragma unroll
  for (int j=0;j<8;j++){
    float w = src[(size_t)(blk*128 + k0 + j)*128 + col];
    unsigned short hi = f2bf(w);
    float r1 = w - bf2f(hi);
    unsigned short md = f2bf(r1);
    float r2 = r1 - bf2f(md);
    Wpk_hi[off+j] = hi;
    Wpk_md[off+j] = md;
    Wpk_lo[off+j] = f2bf(r2);
  }
}

// h = relu(x @ W_node + b_node); h (f32) + hacc (f32 residual/atomic base)
__global__ __launch_bounds__(256) void k_embed_node(
    const float* __restrict__ x, const float* __restrict__ W, const float* __restrict__ b,
    float* __restrict__ h, float* __restrict__ hacc)
{
  int i = blockIdx.x*256 + threadIdx.x;
  if (i >= NN*128) return;
  int n = i >> 7, c = i & 127;
  float acc = b[c];
  const float* xr = x + n*10;
  #pragma unroll
  for (int k=0;k<10;k++) acc = fmaf(xr[k], W[k*128+c], acc);
  acc = fmaxf(acc, 0.0f);
  h[i] = acc; hacc[i] = acc;
}

// PAIR-FUSED per-node projections, 3-term compensated bf16 MFMA, 2 TILES/WAVE.
// Block = 512 threads x 256 nodes x one PAIR:
//   p=0: mats (0,3) -> Pd = (Af+bf, As+bs);  p=1: mats (1,4) -> Ps = (Bf, Bs).
// Each wave: 2 node-tiles (32 nodes) sharing every B-fragment load.
// LDS: hi of both mats (64KB). md+lo terms from L2 (broadcast-hot).
__global__ __launch_bounds__(512,2) void k_nodeproj_mfma(
    const float* __restrict__ h,
    const unsigned short* __restrict__ Wpk_hi, const unsigned short* __restrict__ Wpk_md,
    const unsigned short* __restrict__ Wpk_lo,      // layer base (6 mats)
    const float* __restrict__ bfv, const float* __restrict__ bsv,
    float* __restrict__ Pd, float* __restrict__ Ps)
{
  __shared__ unsigned short wsm[32768];   // 64KB: hi(mA)[0:16384) | hi(mB)[16384:32768)
  int bid = blockIdx.x;
  int p = bid / 79, nblk = bid - p*79;    // 79 blocks/pair, 256 nodes/block
  int mA = p ? 1 : 0;
  int mB = p ? 4 : 3;
  int t = threadIdx.x;
  {
    const unsigned short* s0 = Wpk_hi + (size_t)mA*16384;
    const unsigned short* s1 = Wpk_hi + (size_t)mB*16384;
    #pragma unroll
    for (int ii=0; ii<4; ii++){
      int o = (t + ii*512)*8;
      *(u16x8*)(wsm + o)         = *(const u16x8*)(s0 + o);
      *(u16x8*)(wsm + 16384 + o) = *(const u16x8*)(s1 + o);
    }
  }
  __syncthreads();
  int l = t & 63, w = t >> 6;
  int nb0 = nblk*256 + w*32;              // tile0 = [nb0,nb0+16), tile1 = +16
  if (nb0 + 32 > NN) return;              // NN = 625*32: waves fully valid or not
  bf16x8 ah0[4], am0[4], al0[4], ah1[4], am1[4], al1[4];
  const float* hb0 = h + (size_t)(nb0      + (l&15))*128 + (l>>4)*8;
  const float* hb1 = h + (size_t)(nb0 + 16 + (l&15))*128 + (l>>4)*8;
  #pragma unroll
  for (int ks=0;ks<4;ks++){
    #pragma unroll
    for (int j=0;j<8;j++){
      float v = hb0[ks*32 + j];                             // v >= 0
      unsigned short x0 = (unsigned short)(__float_as_uint(v) >> 16);
      float r1 = v - bf2f(x0);
      unsigned short x1 = (unsigned short)(__float_as_uint(r1) >> 16);
      float r2 = r1 - bf2f(x1);
      ah0[ks][j] = (short)x0; am0[ks][j] = (short)x1; al0[ks][j] = (short)f2bf(r2);
      float u = hb1[ks*32 + j];
      unsigned short y0 = (unsigned short)(__float_as_uint(u) >> 16);
      float s1r = u - bf2f(y0);
      unsigned short y1 = (unsigned short)(__float_as_uint(s1r) >> 16);
      float s2r = s1r - bf2f(y1);
      ah1[ks][j] = (short)y0; am1[ks][j] = (short)y1; al1[ks][j] = (short)f2bf(s2r);
    }
  }
  const unsigned short* wmA = Wpk_md + (size_t)mA*16384 + l*8;
  const unsigned short* wlA = Wpk_lo + (size_t)mA*16384 + l*8;
  const unsigned short* wmB = Wpk_md + (size_t)mB*16384 + l*8;
  const unsigned short* wlB = Wpk_lo + (size_t)mB*16384 + l*8;
  float* OUT = p ? Ps : Pd;
  int col0 = l & 15, rg = (l>>4)*4;
  #pragma unroll
  for (int nt=0; nt<8; nt++){
    f32x4 cA0 = {0.f,0.f,0.f,0.f}, cB0 = {0.f,0.f,0.f,0.f};
    f32x4 cA1 = {0.f,0.f,0.f,0.f}, cB1 = {0.f,0.f,0.f,0.f};
    #pragma unroll
    for (int ks=0;ks<4;ks++){
      int fo = (nt*4+ks)*512;
      bf16x8 bhA = *(const bf16x8*)(wsm + fo + l*8);
      bf16x8 bmA = *(const bf16x8*)(wmA + fo);
      bf16x8 blA = *(const bf16x8*)(wlA + fo);
      cA0 = __builtin_amdgcn_mfma_f32_16x16x32_bf16(al0[ks], bhA, cA0, 0,0,0);
      cA0 = __builtin_amdgcn_mfma_f32_16x16x32_bf16(am0[ks], bmA, cA0, 0,0,0);
      cA0 = __builtin_amdgcn_mfma_f32_16x16x32_bf16(ah0[ks], blA, cA0, 0,0,0);
      cA0 = __builtin_amdgcn_mfma_f32_16x16x32_bf16(am0[ks], bhA, cA0, 0,0,0);
      cA0 = __builtin_amdgcn_mfma_f32_16x16x32_bf16(ah0[ks], bmA, cA0, 0,0,0);
      cA0 = __builtin_amdgcn_mfma_f32_16x16x32_bf16(ah0[ks], bhA, cA0, 0,0,0);
      cA1 = __builtin_amdgcn_mfma_f32_16x16x32_bf16(al1[ks], bhA, cA1, 0,0,0);
      cA1 = __builtin_amdgcn_mfma_f32_16x16x32_bf16(am1[ks], bmA, cA1, 0,0,0);
      cA1 = __builtin_amdgcn_mfma_f32_16x16x32_bf16(ah1[ks], blA, cA1, 0,0,0);
      cA1 = __builtin_amdgcn_mfma_f32_16x16x32_bf16(am1[ks], bhA, cA1, 0,0,0);
      cA1 = __builtin_amdgcn_mfma_f32_16x16x32_bf16(ah1[ks], bmA, cA1, 0,0,0);
      cA1 = __builtin_amdgcn_mfma_f32_16x16x32_bf16(ah1[ks], bhA, cA1, 0,0,0);
      bf16x8 bhB = *(const bf16x8*)(wsm + 16384 + fo + l*8);
      bf16x8 bmB = *(const bf16x8*)(wmB + fo);
      bf16x8 blB = *(const bf16x8*)(wlB + fo);
      cB0 = __builtin_amdgcn_mfma_f32_16x16x32_bf16(al0[ks], bhB, cB0, 0,0,0);
      cB0 = __builtin_amdgcn_mfma_f32_16x16x32_bf16(am0[ks], bmB, cB0, 0,0,0);
      cB0 = __builtin_amdgcn_mfma_f32_16x16x32_bf16(ah0[ks], blB, cB0, 0,0,0);
      cB0 = __builtin_amdgcn_mfma_f32_16x16x32_bf16(am0[ks], bhB, cB0, 0,0,0);
      cB0 = __builtin_amdgcn_mfma_f32_16x16x32_bf16(ah0[ks], bmB, cB0, 0,0,0);
      cB0 = __builtin_amdgcn_mfma_f32_16x16x32_bf16(ah0[ks], bhB, cB0, 0,0,0);
      cB1 = __builtin_amdgcn_mfma_f32_16x16x32_bf16(al1[ks], bhB, cB1, 0,0,0);
      cB1 = __builtin_amdgcn_mfma_f32_16x16x32_bf16(am1[ks], bmB, cB1, 0,0,0);
      cB1 = __builtin_amdgcn_mfma_f32_16x16x32_bf16(ah1[ks], blB, cB1, 0,0,0);
      cB1 = __builtin_amdgcn_mfma_f32_16x16x32_bf16(am1[ks], bhB, cB1, 0,0,0);
      cB1 = __builtin_amdgcn_mfma_f32_16x16x32_bf16(ah1[ks], bmB, cB1, 0,0,0);
      cB1 = __builtin_amdgcn_mfma_f32_16x16x32_bf16(ah1[ks], bhB, cB1, 0,0,0);
    }
    float ba = 0.0f, bb = 0.0f;
    if (!p){ ba = bfv[nt*16+col0]; bb = bsv[nt*16+col0]; }
    #pragma unroll
    for (int r=0;r<4;r++){
      float2 v0 = {cA0[r] + ba, cB0[r] + bb};
      float2 v1 = {cA1[r] + ba, cB1[r] + bb};
      *(float2*)&OUT[(size_t)(nb0      + rg + r)*256 + (nt*16+col0)*2] = v0;
      *(float2*)&OUT[(size_t)(nb0 + 16 + rg + r)*256 + (nt*16+col0)*2] = v1;
    }
  }
}

// Edge kernel (r14/r20 champion, byte-identical): column-quarter blocks with LDS
// weights, quarter-major order. 64 dst-sorted edges x 32 cols, 4 waves of 16.
// e-fragments TRUNC/RNE split in registers; 2-term compensated MFMA;
// run-merged epilogue (2 cols/thread per edge).
__global__ __launch_bounds__(256,4) void k_edge_mfma(
    const float* __restrict__ ea_s, const float* __restrict__ W_edge,
    const float* __restrict__ b_edge,
    const unsigned short* __restrict__ Wpk_hi,  // layer base (6 mats): m=2 (f), m=5 (s)
    const unsigned short* __restrict__ Wpk_md,
    const int2* __restrict__ esd,
    const float* __restrict__ Pd, const float* __restrict__ Ps,
    float* __restrict__ hacc)
{
  __shared__ float wlds[512];              // W_edge rows 0..2 | b_edge
  __shared__ unsigned short bfr[16384];    // 32KB quarter weights
  int bid = blockIdx.x;
  int q = bid / NQB, eg = bid - q*NQB;     // quarter-major order
  int t = threadIdx.x;
  for (int i=t;i<512;i+=256) wlds[i] = (i<384)? W_edge[i] : b_edge[i-384];
  #pragma unroll
  for (int ii=0; ii<8; ii++){
    int idx = t + ii*256;                  // 0..2047
    int f = idx >> 6;                      // frag id: (g<<4)|(term<<3)|(ntl<<2)|ks
    int off = (idx & 63) * 8;
    int g = f >> 4, term = (f>>3)&1, ntl = (f>>2)&1, ks = f&3;
    const unsigned short* src = (term ? Wpk_md : Wpk_hi)
        + (size_t)(g?5:2)*16384 + (size_t)((((q*2+ntl)*4+ks)*512) + off);
    *(u16x8*)(bfr + f*512 + off) = *(const u16x8*)src;
  }
  __syncthreads();
  int l = t & 63, w = t >> 6;
  int e0 = eg*64;
  int row_edge = e0 + w*16 + (l&15);
  float a0 = ea_s[row_edge*3+0], a1 = ea_s[row_edge*3+1], a2 = ea_s[row_edge*3+2];
  int cbase = (l>>4)*8;
  bf16x8 ah[4], al[4];
  #pragma unroll
  for (int ks=0;ks<4;ks++){
    #pragma unroll
    for (int j=0;j<8;j++){
      int c = cbase + ks*32 + j;
      float v = fmaf(a0, wlds[c], fmaf(a1, wlds[128+c], fmaf(a2, wlds[256+c], wlds[384+c])));
      v = fmaxf(v, 0.0f);
      unsigned short hi = (unsigned short)(__float_as_uint(v) >> 16);   // trunc (v>=0)
      ah[ks][j] = (short)hi;
      al[ks][j] = (short)f2bf(v - bf2f(hi));                            // exact remainder
    }
  }
  f32x4 accf[2], accs[2];
  #pragma unroll
  for (int ntl=0; ntl<2; ntl++){
    f32x4 cf = {0.f,0.f,0.f,0.f}, cs = {0.f,0.f,0.f,0.f};
    #pragma unroll
    for (int ks=0; ks<4; ks++){
      bf16x8 bh = *(const bf16x8*)(bfr + ((0<<4)|(0<<3)|(ntl<<2)|ks)*512 + l*8);
      bf16x8 bm = *(const bf16x8*)(bfr + ((0<<4)|(1<<3)|(ntl<<2)|ks)*512 + l*8);
      cf = __builtin_amdgcn_mfma_f32_16x16x32_bf16(ah[ks], bh, cf, 0,0,0);
      cf = __builtin_amdgcn_mfma_f32_16x16x32_bf16(ah[ks], bm, cf, 0,0,0);
      cf = __builtin_amdgcn_mfma_f32_16x16x32_bf16(al[ks], bh, cf, 0,0,0);
      bf16x8 sh = *(const bf16x8*)(bfr + ((1<<4)|(0<<3)|(ntl<<2)|ks)*512 + l*8);
      bf16x8 sm = *(const bf16x8*)(bfr + ((1<<4)|(1<<3)|(ntl<<2)|ks)*512 + l*8);
      cs = __builtin_amdgcn_mfma_f32_16x16x32_bf16(ah[ks], sh, cs, 0,0,0);
      cs = __builtin_amdgcn_mfma_f32_16x16x32_bf16(ah[ks], sm, cs, 0,0,0);
      cs = __builtin_amdgcn_mfma_f32_16x16x32_bf16(al[ks], sh, cs, 0,0,0);
    }
    accf[ntl] = cf; accs[ntl] = cs;
  }
  int eb = e0 + w*16, col0 = l & 15, rg = (l>>4)*4;
  int cA = (q*2+0)*16 + col0;
  int cB = (q*2+1)*16 + col0;
  int prev_d = -1;
  float m0 = 0.f, m1 = 0.f;
  float2 pd0, pd1;
  #pragma unroll
  for (int r=0;r<4;r++){
    int pp = eb + rg + r;
    int2 sd = esd[pp];
    int s = sd.x, d = sd.y;
    if (d != prev_d){
      if (prev_d >= 0){
        atomicAdd(hacc + (size_t)prev_d*128 + cA, m0);
        atomicAdd(hacc + (size_t)prev_d*128 + cB, m1);
      }
      prev_d = d;
      pd0 = *(const float2*)(Pd + (size_t)d*256 + cA*2);
      pd1 = *(const float2*)(Pd + (size_t)d*256 + cB*2);
      m0 = 0.f; m1 = 0.f;
    }
    float2 ps0 = *(const float2*)(Ps + (size_t)s*256 + cA*2);
    float2 ps1 = *(const float2*)(Ps + (size_t)s*256 + cB*2);
    m0 += fastmsg(accf[0][r] + pd0.x + ps0.x, accs[0][r] + pd0.y + ps0.y);
    m1 += fastmsg(accf[1][r] + pd1.x + ps1.x, accs[1][r] + pd1.y + ps1.y);
  }
  atomicAdd(hacc + (size_t)prev_d*128 + cA, m0);
  atomicAdd(hacc + (size_t)prev_d*128 + cB, m1);
}

// h_new = relu(BN(hacc)) (+ h_in if addres); float4-vectorized (c4 = 4-aligned channel)
__global__ __launch_bounds__(256) void k_bn(
    const float* __restrict__ hacc, const float* __restrict__ hin,
    const float* __restrict__ gam, const float* __restrict__ bet,
    const float* __restrict__ mu, const float* __restrict__ var,
    float* __restrict__ hout, float* __restrict__ haccout, int addres)
{
  int i4 = blockIdx.x*256 + threadIdx.x;
  if (i4 >= NN*32) return;
  int c4 = (i4 & 31) * 4;
  float4 a = *(const float4*)&hacc[(size_t)i4*4];
  float4 g = *(const float4*)&gam[c4];
  float4 b = *(const float4*)&bet[c4];
  float4 m = *(const float4*)&mu[c4];
  float4 vv = *(const float4*)&var[c4];
  float4 o;
  o.x = fmaxf((a.x - m.x)*(g.x*rsqrtf(vv.x+EPSV)) + b.x, 0.0f);
  o.y = fmaxf((a.y - m.y)*(g.y*rsqrtf(vv.y+EPSV)) + b.y, 0.0f);
  o.z = fmaxf((a.z - m.z)*(g.z*rsqrtf(vv.z+EPSV)) + b.z, 0.0f);
  o.w = fmaxf((a.w - m.w)*(g.w*rsqrtf(vv.w+EPSV)) + b.w, 0.0f);
  if (addres){
    float4 hi4 = *(const float4*)&hin[(size_t)i4*4];
    o.x += hi4.x; o.y += hi4.y; o.z += hi4.z; o.w += hi4.w;
  }
  *(float4*)&hout[(size_t)i4*4] = o;
  *(float4*)&haccout[(size_t)i4*4] = o;
}

// Final layer: BN (+residual) fused with pooling atomics.
__global__ __launch_bounds__(256) void k_bn_pool(
    const float* __restrict__ hacc, const float* __restrict__ hin,
    const float* __restrict__ gam, const float* __restrict__ bet,
    const float* __restrict__ mu, const float* __restrict__ var,
    const int* __restrict__ batch,
    float* __restrict__ psum, float* __restrict__ pmax, float* __restrict__ pcnt,
    int addres)
{
  int i = blockIdx.x*256 + threadIdx.x;
  if (i >= NN*128) return;
  int n = i >> 7, c = i & 127;
  float scale = gam[c]*rsqrtf(var[c]+EPSV);
  float tv = (hacc[i]-mu[c])*scale + bet[c];
  tv = fmaxf(tv, 0.0f);
  if (addres) tv += hin[i];
  int b = batch[n];
  atomicAdd(&psum[b*128+c], tv);
  atomicMax((unsigned int*)&pmax[b*128+c], __float_as_uint(tv));  // valid: tv >= 0
  if (c == 0) atomicAdd(&pcnt[b], 1.0f);
}

__global__ __launch_bounds__(256) void k_mlp1(
    const float* __restrict__ psum, const float* __restrict__ pmax, const float* __restrict__ pcnt,
    const float* __restrict__ W1, const float* __restrict__ b1,
    const float* __restrict__ g1g, const float* __restrict__ g1b,
    const float* __restrict__ g1m, const float* __restrict__ g1v,
    float* __restrict__ out)
{
  int i = blockIdx.x*256 + threadIdx.x;
  int g = i >> 8, c = i & 255;
  float inv = 1.0f / fmaxf(pcnt[g], 1.0f);
  float acc = b1[c];
  for (int k=0;k<128;k++) acc = fmaf(psum[g*128+k]*inv, W1[k*256+c], acc);
  for (int k=0;k<128;k++) acc = fmaf(pmax[g*128+k],     W1[(128+k)*256+c], acc);
  for (int k=0;k<128;k++) acc = fmaf(psum[g*128+k],     W1[(256+k)*256+c], acc);
  float scale = g1g[c]*rsqrtf(g1v[c]+EPSV);
  acc = (acc - g1m[c])*scale + g1b[c];
  out[i] = fmaxf(acc, 0.0f);
}

__global__ __launch_bounds__(256) void k_mlp2(
    const float* __restrict__ g1, const float* __restrict__ W2, const float* __restrict__ b2,
    const float* __restrict__ g2g, const float* __restrict__ g2b,
    const float* __restrict__ g2m, const float* __restrict__ g2v,
    float* __restrict__ out)
{
  int i = blockIdx.x*256 + threadIdx.x;
  int g = i >> 7, c = i & 127;
  float acc = b2[c];
  for (int k=0;k<256;k++) acc = fmaf(g1[g*256+k], W2[k*128+c], acc);
  float scale = g2g[c]*rsqrtf(g2v[c]+EPSV);
  acc = (acc - g2m[c])*scale + g2b[c];
  out[i] = fmaxf(acc, 0.0f);
}

__global__ __launch_bounds__(256) void k_mlp3(
    const float* __restrict__ g2, const float* __restrict__ W3, const float* __restrict__ b3,
    float* __restrict__ out)
{
  int i = blockIdx.x*256 + threadIdx.x;
  int g = i >> 6, c = i & 63;
  float acc = b3[c];
  for (int k=0;k<128;k++) acc = fmaf(g2[g*128+k], W3[k*64+c], acc);
  out[i] = fmaxf(acc, 0.0f);
}

__global__ __launch_bounds__(256) void k_heads(
    const float* __restrict__ g3,
    const float* __restrict__ Wv, const float* __restrict__ bv,
    const float* __restrict__ We, const float* __restrict__ be,
    const float* __restrict__ Wd, const float* __restrict__ bd,
    const float* __restrict__ Wh, const float* __restrict__ bh,
    float* __restrict__ out)
{
  int g = blockIdx.x*256 + threadIdx.x;
  if (g >= NG) return;
  float a0=bv[0], a1=be[0], a2=bd[0], a3=bh[0];
  for (int k=0;k<64;k++){
    float xv = g3[g*64+k];
    a0 = fmaf(xv, Wv[k], a0);
    a1 = fmaf(xv, We[k], a1);
    a2 = fmaf(xv, Wd[k], a2);
    a3 = fmaf(xv, Wh[k], a3);
  }
  out[g] = a0; out[NG+g] = a1; out[2*NG+g] = a2; out[3*NG+g] = a3;
}

extern "C" void kernel_launch(void* const* d_in, const int* in_sizes, int n_in,
                              void* d_out, int out_size, void* d_ws, size_t ws_size,
                              hipStream_t stream)
{
  const float* x         = (const float*)d_in[0];
  const float* edge_attr = (const float*)d_in[1];
  const int*   ei        = (const int*)d_in[2];
  const int*   batch     = (const int*)d_in[3];
  const float* W_node    = (const float*)d_in[4];
  const float* b_node    = (const float*)d_in[5];
  const float* W_edge    = (const float*)d_in[6];
  const float* b_edge    = (const float*)d_in[7];
  const float* Wf        = (const float*)d_in[8];
  const float* bf        = (const float*)d_in[9];
  const float* Ws        = (const float*)d_in[10];
  const float* bs        = (const float*)d_in[11];
  const float* bn_g      = (const float*)d_in[12];
  const float* bn_b      = (const float*)d_in[13];
  const float* bn_m      = (const float*)d_in[14];
  const float* bn_v      = (const float*)d_in[15];
  const float* W1        = (const float*)d_in[16];
  const float* b1        = (const float*)d_in[17];
  const float* bn1_g     = (const float*)d_in[18];
  const float* bn1_b     = (const float*)d_in[19];
  const float* bn1_m     = (const float*)d_in[20];
  const float* bn1_v     = (const float*)d_in[21];
  const float* W2        = (const float*)d_in[22];
  const float* b2        = (const float*)d_in[23];
  const float* bn2_g     = (const float*)d_in[24];
  const float* bn2_b     = (const float*)d_in[25];
  const float* bn2_m     = (const float*)d_in[26];
  const float* bn2_v     = (const float*)d_in[27];
  const float* W3        = (const float*)d_in[28];
  const float* b3        = (const float*)d_in[29];
  const float* Wv        = (const float*)d_in[30];
  const float* bv        = (const float*)d_in[31];
  const float* W_en      = (const float*)d_in[32];
  const float* b_en      = (const float*)d_in[33];
  const float* Wd        = (const float*)d_in[34];
  const float* bd        = (const float*)d_in[35];
  const float* Wh        = (const float*)d_in[36];
  const float* bh        = (const float*)d_in[37];

  float* wsf  = (float*)d_ws;
  float* h    = wsf;                          // 2,560,000
  float* hacc = wsf + 2560000;                // 2,560,000
  float* Pd   = wsf + 5120000;                // 5,120,000 (float2/elem)
  float* Ps   = wsf + 10240000;               // 5,120,000
  unsigned short* Wpk_hi = (unsigned short*)(wsf + 15360000); // 983,040 shorts
  unsigned short* Wpk_md = (unsigned short*)(wsf + 15851520); // 983,040 shorts
  unsigned short* Wpk_lo = (unsigned short*)(wsf + 16343040); // 983,040 shorts
  float* psum = wsf + 16834560;               // 32768
  float* pmax = psum + 32768;                 // 32768
  float* pcnt = pmax + 32768;                 // 256
  float* g1   = pcnt + 256;                   // 65536
  float* g2   = g1 + 65536;                   // 32768
  float* g3   = g2 + 32768;                   // 16384
  int*   deg  = (int*)(wsf + 16982272);       // 20000
  int*   start= deg + 20000;                  // 20000
  int*   cur  = start + 20000;                // 20000
  int2*  esd  = (int2*)(cur + 20000);         // 160000 int2 = 320000 ints
  float* ea_s = (float*)(cur + 20000 + 320000); // 480000

  // one-time: dst-sort
  hipMemsetAsync(deg, 0, 20000*sizeof(int), stream);
  k_hist<<<(NE+255)/256, 256, 0, stream>>>(ei, deg);
  k_scan<<<1, 1024, 0, stream>>>(deg, start, cur);
  k_scatter<<<(NE+255)/256, 256, 0, stream>>>(ei, edge_attr, cur, esd, ea_s);

  k_pack_w<<<480, 256, 0, stream>>>(Wf, Ws, Wpk_hi, Wpk_md, Wpk_lo);
  k_embed_node<<<(NN*128+255)/256, 256, 0, stream>>>(x, W_node, b_node, h, hacc);
  hipMemsetAsync(psum, 0, (size_t)(32768+32768+256)*sizeof(float), stream);

  for (int i=0;i<10;i++){
    const unsigned short* WH = Wpk_hi + (size_t)i*6*16384;
    const unsigned short* WM = Wpk_md + (size_t)i*6*16384;
    const unsigned short* WL = Wpk_lo + (size_t)i*6*16384;
    k_nodeproj_mfma<<<158, 512, 0, stream>>>(h, WH, WM, WL,
        bf + i*128, bs + i*128, Pd, Ps);
    k_edge_mfma<<<4*NQB, 256, 0, stream>>>(ea_s, W_edge, b_edge,
        WH, WM, esd, Pd, Ps, hacc);
    if (i < 9)
      k_bn<<<(NN*32+255)/256, 256, 0, stream>>>(hacc, h,
          bn_g + i*128, bn_b + i*128, bn_m + i*128, bn_v + i*128, h, hacc, i&1);
    else
      k_bn_pool<<<(NN*128+255)/256, 256, 0, stream>>>(hacc, h,
          bn_g + i*128, bn_b + i*128, bn_m + i*128, bn_v + i*128,
          batch, psum, pmax, pcnt, i&1);
  }

  k_mlp1<<<(NG*256)/256, 256, 0, stream>>>(psum, pmax, pcnt, W1, b1, bn1_g, bn1_b, bn1_m, bn1_v, g1);
  k_mlp2<<<(NG*128)/256, 256, 0, stream>>>(g1, W2, b2, bn2_g, bn2_b, bn2_m, bn2_v, g2);
  k_mlp3<<<(NG*64)/256, 256, 0, stream>>>(g2, W3, b3, g3);
  k_heads<<<1, 256, 0, stream>>>(g3, Wv, bv, W_en, b_en, Wd, bd, Wh, bh, (float*)d_out);
}

// Round 22
// 1273.566 us; speedup vs baseline: 1.0217x; 1.0217x over previous
//
#include <hip/hip_runtime.h>
#include <hip/hip_bf16.h>
#include <math.h>

#define NN 20000
#define NE 160000
#define NG 256
#define EPSV 1e-5f
#define NQB 2500   // edge-groups of 64

typedef short bf16x8 __attribute__((ext_vector_type(8)));
typedef unsigned short u16x8 __attribute__((ext_vector_type(8)));
typedef float f32x4 __attribute__((ext_vector_type(4)));

__device__ __forceinline__ unsigned short f2bf(float f){
  unsigned int u = __float_as_uint(f);
  unsigned int r = (u + 0x7fffu + ((u>>16)&1u)) >> 16;
  return (unsigned short)r;
}
__device__ __forceinline__ float bf2f(unsigned short h){
  return __uint_as_float(((unsigned int)h) << 16);
}
__device__ __forceinline__ float fastmsg(float f, float sv){
  float sg = __builtin_amdgcn_rcpf(1.0f + __expf(-f));
  float sp = fmaxf(sv, 0.0f) + __logf(1.0f + __expf(-fabsf(sv)));
  return sg * sp;
}

// ---- one-time: dst-sort of edges (counting sort) ----
__global__ __launch_bounds__(256) void k_hist(const int* __restrict__ ei, int* __restrict__ deg){
  int e = blockIdx.x*256 + threadIdx.x;
  if (e < NE) atomicAdd(&deg[ei[NE+e]], 1);
}
__global__ __launch_bounds__(1024) void k_scan(const int* __restrict__ deg,
                                               int* __restrict__ start, int* __restrict__ cur){
  __shared__ int part[1024];
  int t = threadIdx.x;
  int base = t*20;
  int s = 0;
  for (int j=0;j<20;j++){ int i = base+j; if (i<NN) s += deg[i]; }
  part[t] = s; __syncthreads();
  for (int off=1; off<1024; off<<=1){
    int v = (t >= off) ? part[t-off] : 0;
    __syncthreads();
    part[t] += v;
    __syncthreads();
  }
  int run = (t>0) ? part[t-1] : 0;
  for (int j=0;j<20;j++){
    int i = base+j;
    if (i<NN){ start[i] = run; cur[i] = run; run += deg[i]; }
  }
}
__global__ __launch_bounds__(256) void k_scatter(
    const int* __restrict__ ei, const float* __restrict__ eattr,
    int* __restrict__ cur, int2* __restrict__ esd, float* __restrict__ ea_s){
  int e = blockIdx.x*256 + threadIdx.x;
  if (e >= NE) return;
  int d = ei[NE+e];
  int p = atomicAdd(&cur[d], 1);
  esd[p] = make_int2(ei[e], d);
  ea_s[p*3+0] = eattr[e*3+0];
  ea_s[p*3+1] = eattr[e*3+1];
  ea_s[p*3+2] = eattr[e*3+2];
}

// ---- one-time: pack ALL weight blocks into MFMA B-frag layout, 3-term bf16 split.
// matrix id m = (L*2+g)*3 + blk  (g: 0=f,1=s; blk: 0=dst,1=src,2=e)
// frag (nt,ks): lane l takes B[k=ks*32+(l>>4)*8+j][col=nt*16+(l&15)]
__global__ __launch_bounds__(256) void k_pack_w(
    const float* __restrict__ Wf, const float* __restrict__ Ws,
    unsigned short* __restrict__ Wpk_hi, unsigned short* __restrict__ Wpk_md,
    unsigned short* __restrict__ Wpk_lo)
{
  int idx = blockIdx.x*256 + threadIdx.x;   // 60 * 2048 = 122880
  if (idx >= 122880) return;
  int l = idx & 63, ks = (idx>>6)&3, nt = (idx>>8)&7;
  int m = idx >> 11;            // 0..59
  int blk = m % 3, gL = m / 3;
  int g = gL & 1, L = gL >> 1;
  const float* src = (g ? Ws : Wf) + (size_t)L*384*128;
  size_t off = (size_t)m*16384 + (nt*4+ks)*512 + l*8;
  int col = nt*16 + (l&15), k0 = ks*32 + (l>>4)*8;
  #pragma unroll
  for (int j=0;j<8;j++){
    float w = src[(size_t)(blk*128 + k0 + j)*128 + col];
    unsigned short hi = f2bf(w);
    float r1 = w - bf2f(hi);
    unsigned short md = f2bf(r1);
    float r2 = r1 - bf2f(md);
    Wpk_hi[off+j] = hi;
    Wpk_md[off+j] = md;
    Wpk_lo[off+j] = f2bf(r2);
  }
}

// h = relu(x @ W_node + b_node); h (f32) + hacc (f32 residual/atomic base)
__global__ __launch_bounds__(256) void k_embed_node(
    const float* __restrict__ x, const float* __restrict__ W, const float* __restrict__ b,
    float* __restrict__ h, float* __restrict__ hacc)
{
  int i = blockIdx.x*256 + threadIdx.x;
  if (i >= NN*128) return;
  int n = i >> 7, c = i & 127;
  float acc = b[c];
  const float* xr = x + n*10;
  #pragma unroll
  for (int k=0;k<10;k++) acc = fmaf(xr[k], W[k*128+c], acc);
  acc = fmaxf(acc, 0.0f);
  h[i] = acc; hacc[i] = acc;
}

// PAIR-FUSED per-node projections (r20 champion version), 3-term compensated
// bf16 MFMA. Block = 512 threads x 128 nodes x one PAIR:
//   p=0: mats (0,3) -> Pd = (Af+bf, As+bs);  p=1: mats (1,4) -> Ps = (Bf, Bs).
// Reads h ONCE per pair; writes DENSE float2. LDS: hi of both mats (64KB);
// md+lo terms from L2 (broadcast-hot).
__global__ __launch_bounds__(512,2) void k_nodeproj_mfma(
    const float* __restrict__ h,
    const unsigned short* __restrict__ Wpk_hi, const unsigned short* __restrict__ Wpk_md,
    const unsigned short* __restrict__ Wpk_lo,      // layer base (6 mats)
    const float* __restrict__ bfv, const float* __restrict__ bsv,
    float* __restrict__ Pd, float* __restrict__ Ps)
{
  __shared__ unsigned short wsm[32768];   // 64KB: hi(mA)[0:16384) | hi(mB)[16384:32768)
  int bid = blockIdx.x;
  int p = bid / 157, nblk = bid - p*157;
  int mA = p ? 1 : 0;             // f-gate matrix
  int mB = p ? 4 : 3;             // s-gate matrix
  int t = threadIdx.x;
  {
    const unsigned short* s0 = Wpk_hi + (size_t)mA*16384;
    const unsigned short* s1 = Wpk_hi + (size_t)mB*16384;
    #pragma unroll
    for (int ii=0; ii<4; ii++){
      int o = (t + ii*512)*8;
      *(u16x8*)(wsm + o)         = *(const u16x8*)(s0 + o);
      *(u16x8*)(wsm + 16384 + o) = *(const u16x8*)(s1 + o);
    }
  }
  __syncthreads();
  int l = t & 63, w = t >> 6;
  int nb = nblk*128 + w*16;
  if (nb + 16 > NN) return;     // tail waves; no barriers after this point
  const float* hb = h + (size_t)(nb + (l&15))*128 + (l>>4)*8;
  bf16x8 ah[4], am[4], al[4];
  #pragma unroll
  for (int ks=0;ks<4;ks++){
    #pragma unroll
    for (int j=0;j<8;j++){
      float v = hb[ks*32 + j];                              // v >= 0
      unsigned short x0 = (unsigned short)(__float_as_uint(v) >> 16);   // trunc
      float r1 = v - bf2f(x0);                              // exact
      unsigned short x1 = (unsigned short)(__float_as_uint(r1) >> 16);  // trunc
      float r2 = r1 - bf2f(x1);                             // exact
      ah[ks][j] = (short)x0; am[ks][j] = (short)x1; al[ks][j] = (short)f2bf(r2);
    }
  }
  const unsigned short* wmA = Wpk_md + (size_t)mA*16384 + l*8;
  const unsigned short* wlA = Wpk_lo + (size_t)mA*16384 + l*8;
  const unsigned short* wmB = Wpk_md + (size_t)mB*16384 + l*8;
  const unsigned short* wlB = Wpk_lo + (size_t)mB*16384 + l*8;
  float* OUT = p ? Ps : Pd;
  int col0 = l & 15, rg = (l>>4)*4;
  #pragma unroll
  for (int nt=0; nt<8; nt++){
    f32x4 cA = {0.f,0.f,0.f,0.f}, cB = {0.f,0.f,0.f,0.f};
    #pragma unroll
    for (int ks=0;ks<4;ks++){
      int fo = (nt*4+ks)*512;
      bf16x8 bhA = *(const bf16x8*)(wsm + fo + l*8);
      bf16x8 bmA = *(const bf16x8*)(wmA + fo);
      bf16x8 blA = *(const bf16x8*)(wlA + fo);
      cA = __builtin_amdgcn_mfma_f32_16x16x32_bf16(al[ks], bhA, cA, 0,0,0);
      cA = __builtin_amdgcn_mfma_f32_16x16x32_bf16(am[ks], bmA, cA, 0,0,0);
      cA = __builtin_amdgcn_mfma_f32_16x16x32_bf16(ah[ks], blA, cA, 0,0,0);
      cA = __builtin_amdgcn_mfma_f32_16x16x32_bf16(am[ks], bhA, cA, 0,0,0);
      cA = __builtin_amdgcn_mfma_f32_16x16x32_bf16(ah[ks], bmA, cA, 0,0,0);
      cA = __builtin_amdgcn_mfma_f32_16x16x32_bf16(ah[ks], bhA, cA, 0,0,0);
      bf16x8 bhB = *(const bf16x8*)(wsm + 16384 + fo + l*8);
      bf16x8 bmB = *(const bf16x8*)(wmB + fo);
      bf16x8 blB = *(const bf16x8*)(wlB + fo);
      cB = __builtin_amdgcn_mfma_f32_16x16x32_bf16(al[ks], bhB, cB, 0,0,0);
      cB = __builtin_amdgcn_mfma_f32_16x16x32_bf16(am[ks], bmB, cB, 0,0,0);
      cB = __builtin_amdgcn_mfma_f32_16x16x32_bf16(ah[ks], blB, cB, 0,0,0);
      cB = __builtin_amdgcn_mfma_f32_16x16x32_bf16(am[ks], bhB, cB, 0,0,0);
      cB = __builtin_amdgcn_mfma_f32_16x16x32_bf16(ah[ks], bmB, cB, 0,0,0);
      cB = __builtin_amdgcn_mfma_f32_16x16x32_bf16(ah[ks], bhB, cB, 0,0,0);
    }
    float ba = 0.0f, bb = 0.0f;
    if (!p){ ba = bfv[nt*16+col0]; bb = bsv[nt*16+col0]; }
    #pragma unroll
    for (int r=0;r<4;r++){
      float2 v2 = {cA[r] + ba, cB[r] + bb};
      *(float2*)&OUT[(size_t)(nb+rg+r)*256 + (nt*16+col0)*2] = v2;
    }
  }
}

// Edge kernel (r14/r20 champion, byte-identical): column-quarter blocks with LDS
// weights, quarter-major order. 64 dst-sorted edges x 32 cols, 4 waves of 16.
// e-fragments TRUNC/RNE split in registers; 2-term compensated MFMA;
// run-merged epilogue (2 cols/thread per edge).
__global__ __launch_bounds__(256,4) void k_edge_mfma(
    const float* __restrict__ ea_s, const float* __restrict__ W_edge,
    const float* __restrict__ b_edge,
    const unsigned short* __restrict__ Wpk_hi,  // layer base (6 mats): m=2 (f), m=5 (s)
    const unsigned short* __restrict__ Wpk_md,
    const int2* __restrict__ esd,
    const float* __restrict__ Pd, const float* __restrict__ Ps,
    float* __restrict__ hacc)
{
  __shared__ float wlds[512];              // W_edge rows 0..2 | b_edge
  __shared__ unsigned short bfr[16384];    // 32KB quarter weights
  int bid = blockIdx.x;
  int q = bid / NQB, eg = bid - q*NQB;     // quarter-major order
  int t = threadIdx.x;
  for (int i=t;i<512;i+=256) wlds[i] = (i<384)? W_edge[i] : b_edge[i-384];
  #pragma unroll
  for (int ii=0; ii<8; ii++){
    int idx = t + ii*256;                  // 0..2047
    int f = idx >> 6;                      // frag id: (g<<4)|(term<<3)|(ntl<<2)|ks
    int off = (idx & 63) * 8;
    int g = f >> 4, term = (f>>3)&1, ntl = (f>>2)&1, ks = f&3;
    const unsigned short* src = (term ? Wpk_md : Wpk_hi)
        + (size_t)(g?5:2)*16384 + (size_t)((((q*2+ntl)*4+ks)*512) + off);
    *(u16x8*)(bfr + f*512 + off) = *(const u16x8*)src;
  }
  __syncthreads();
  int l = t & 63, w = t >> 6;
  int e0 = eg*64;
  int row_edge = e0 + w*16 + (l&15);
  float a0 = ea_s[row_edge*3+0], a1 = ea_s[row_edge*3+1], a2 = ea_s[row_edge*3+2];
  int cbase = (l>>4)*8;
  bf16x8 ah[4], al[4];
  #pragma unroll
  for (int ks=0;ks<4;ks++){
    #pragma unroll
    for (int j=0;j<8;j++){
      int c = cbase + ks*32 + j;
      float v = fmaf(a0, wlds[c], fmaf(a1, wlds[128+c], fmaf(a2, wlds[256+c], wlds[384+c])));
      v = fmaxf(v, 0.0f);
      unsigned short hi = (unsigned short)(__float_as_uint(v) >> 16);   // trunc (v>=0)
      ah[ks][j] = (short)hi;
      al[ks][j] = (short)f2bf(v - bf2f(hi));                            // exact remainder
    }
  }
  f32x4 accf[2], accs[2];
  #pragma unroll
  for (int ntl=0; ntl<2; ntl++){
    f32x4 cf = {0.f,0.f,0.f,0.f}, cs = {0.f,0.f,0.f,0.f};
    #pragma unroll
    for (int ks=0; ks<4; ks++){
      bf16x8 bh = *(const bf16x8*)(bfr + ((0<<4)|(0<<3)|(ntl<<2)|ks)*512 + l*8);
      bf16x8 bm = *(const bf16x8*)(bfr + ((0<<4)|(1<<3)|(ntl<<2)|ks)*512 + l*8);
      cf = __builtin_amdgcn_mfma_f32_16x16x32_bf16(ah[ks], bh, cf, 0,0,0);
      cf = __builtin_amdgcn_mfma_f32_16x16x32_bf16(ah[ks], bm, cf, 0,0,0);
      cf = __builtin_amdgcn_mfma_f32_16x16x32_bf16(al[ks], bh, cf, 0,0,0);
      bf16x8 sh = *(const bf16x8*)(bfr + ((1<<4)|(0<<3)|(ntl<<2)|ks)*512 + l*8);
      bf16x8 sm = *(const bf16x8*)(bfr + ((1<<4)|(1<<3)|(ntl<<2)|ks)*512 + l*8);
      cs = __builtin_amdgcn_mfma_f32_16x16x32_bf16(ah[ks], sh, cs, 0,0,0);
      cs = __builtin_amdgcn_mfma_f32_16x16x32_bf16(ah[ks], sm, cs, 0,0,0);
      cs = __builtin_amdgcn_mfma_f32_16x16x32_bf16(al[ks], sh, cs, 0,0,0);
    }
    accf[ntl] = cf; accs[ntl] = cs;
  }
  int eb = e0 + w*16, col0 = l & 15, rg = (l>>4)*4;
  int cA = (q*2+0)*16 + col0;
  int cB = (q*2+1)*16 + col0;
  int prev_d = -1;
  float m0 = 0.f, m1 = 0.f;
  float2 pd0, pd1;
  #pragma unroll
  for (int r=0;r<4;r++){
    int pp = eb + rg + r;
    int2 sd = esd[pp];
    int s = sd.x, d = sd.y;
    if (d != prev_d){
      if (prev_d >= 0){
        atomicAdd(hacc + (size_t)prev_d*128 + cA, m0);
        atomicAdd(hacc + (size_t)prev_d*128 + cB, m1);
      }
      prev_d = d;
      pd0 = *(const float2*)(Pd + (size_t)d*256 + cA*2);
      pd1 = *(const float2*)(Pd + (size_t)d*256 + cB*2);
      m0 = 0.f; m1 = 0.f;
    }
    float2 ps0 = *(const float2*)(Ps + (size_t)s*256 + cA*2);
    float2 ps1 = *(const float2*)(Ps + (size_t)s*256 + cB*2);
    m0 += fastmsg(accf[0][r] + pd0.x + ps0.x, accs[0][r] + pd0.y + ps0.y);
    m1 += fastmsg(accf[1][r] + pd1.x + ps1.x, accs[1][r] + pd1.y + ps1.y);
  }
  atomicAdd(hacc + (size_t)prev_d*128 + cA, m0);
  atomicAdd(hacc + (size_t)prev_d*128 + cB, m1);
}

// h_new = relu(BN(hacc)) (+ h_in if addres); float4-vectorized
__global__ __launch_bounds__(256) void k_bn(
    const float* __restrict__ hacc, const float* __restrict__ hin,
    const float* __restrict__ gam, const float* __restrict__ bet,
    const float* __restrict__ mu, const float* __restrict__ var,
    float* __restrict__ hout, float* __restrict__ haccout, int addres)
{
  int i4 = blockIdx.x*256 + threadIdx.x;
  if (i4 >= NN*32) return;
  int c4 = (i4 & 31) * 4;
  float4 a = *(const float4*)&hacc[(size_t)i4*4];
  float4 g = *(const float4*)&gam[c4];
  float4 b = *(const float4*)&bet[c4];
  float4 m = *(const float4*)&mu[c4];
  float4 vv = *(const float4*)&var[c4];
  float4 o;
  o.x = fmaxf((a.x - m.x)*(g.x*rsqrtf(vv.x+EPSV)) + b.x, 0.0f);
  o.y = fmaxf((a.y - m.y)*(g.y*rsqrtf(vv.y+EPSV)) + b.y, 0.0f);
  o.z = fmaxf((a.z - m.z)*(g.z*rsqrtf(vv.z+EPSV)) + b.z, 0.0f);
  o.w = fmaxf((a.w - m.w)*(g.w*rsqrtf(vv.w+EPSV)) + b.w, 0.0f);
  if (addres){
    float4 hi4 = *(const float4*)&hin[(size_t)i4*4];
    o.x += hi4.x; o.y += hi4.y; o.z += hi4.z; o.w += hi4.w;
  }
  *(float4*)&hout[(size_t)i4*4] = o;
  *(float4*)&haccout[(size_t)i4*4] = o;
}

// Final layer: BN (+residual) fused with pooling atomics.
__global__ __launch_bounds__(256) void k_bn_pool(
    const float* __restrict__ hacc, const float* __restrict__ hin,
    const float* __restrict__ gam, const float* __restrict__ bet,
    const float* __restrict__ mu, const float* __restrict__ var,
    const int* __restrict__ batch,
    float* __restrict__ psum, float* __restrict__ pmax, float* __restrict__ pcnt,
    int addres)
{
  int i = blockIdx.x*256 + threadIdx.x;
  if (i >= NN*128) return;
  int n = i >> 7, c = i & 127;
  float scale = gam[c]*rsqrtf(var[c]+EPSV);
  float tv = (hacc[i]-mu[c])*scale + bet[c];
  tv = fmaxf(tv, 0.0f);
  if (addres) tv += hin[i];
  int b = batch[n];
  atomicAdd(&psum[b*128+c], tv);
  atomicMax((unsigned int*)&pmax[b*128+c], __float_as_uint(tv));  // valid: tv >= 0
  if (c == 0) atomicAdd(&pcnt[b], 1.0f);
}

__global__ __launch_bounds__(256) void k_mlp1(
    const float* __restrict__ psum, const float* __restrict__ pmax, const float* __restrict__ pcnt,
    const float* __restrict__ W1, const float* __restrict__ b1,
    const float* __restrict__ g1g, const float* __restrict__ g1b,
    const float* __restrict__ g1m, const float* __restrict__ g1v,
    float* __restrict__ out)
{
  int i = blockIdx.x*256 + threadIdx.x;
  int g = i >> 8, c = i & 255;
  float inv = 1.0f / fmaxf(pcnt[g], 1.0f);
  float acc = b1[c];
  for (int k=0;k<128;k++) acc = fmaf(psum[g*128+k]*inv, W1[k*256+c], acc);
  for (int k=0;k<128;k++) acc = fmaf(pmax[g*128+k],     W1[(128+k)*256+c], acc);
  for (int k=0;k<128;k++) acc = fmaf(psum[g*128+k],     W1[(256+k)*256+c], acc);
  float scale = g1g[c]*rsqrtf(g1v[c]+EPSV);
  acc = (acc - g1m[c])*scale + g1b[c];
  out[i] = fmaxf(acc, 0.0f);
}

__global__ __launch_bounds__(256) void k_mlp2(
    const float* __restrict__ g1, const float* __restrict__ W2, const float* __restrict__ b2,
    const float* __restrict__ g2g, const float* __restrict__ g2b,
    const float* __restrict__ g2m, const float* __restrict__ g2v,
    float* __restrict__ out)
{
  int i = blockIdx.x*256 + threadIdx.x;
  int g = i >> 7, c = i & 127;
  float acc = b2[c];
  for (int k=0;k<256;k++) acc = fmaf(g1[g*256+k], W2[k*128+c], acc);
  float scale = g2g[c]*rsqrtf(g2v[c]+EPSV);
  acc = (acc - g2m[c])*scale + g2b[c];
  out[i] = fmaxf(acc, 0.0f);
}

__global__ __launch_bounds__(256) void k_mlp3(
    const float* __restrict__ g2, const float* __restrict__ W3, const float* __restrict__ b3,
    float* __restrict__ out)
{
  int i = blockIdx.x*256 + threadIdx.x;
  int g = i >> 6, c = i & 63;
  float acc = b3[c];
  for (int k=0;k<128;k++) acc = fmaf(g2[g*128+k], W3[k*64+c], acc);
  out[i] = fmaxf(acc, 0.0f);
}

__global__ __launch_bounds__(256) void k_heads(
    const float* __restrict__ g3,
    const float* __restrict__ Wv, const float* __restrict__ bv,
    const float* __restrict__ We, const float* __restrict__ be,
    const float* __restrict__ Wd, const float* __restrict__ bd,
    const float* __restrict__ Wh, const float* __restrict__ bh,
    float* __restrict__ out)
{
  int g = blockIdx.x*256 + threadIdx.x;
  if (g >= NG) return;
  float a0=bv[0], a1=be[0], a2=bd[0], a3=bh[0];
  for (int k=0;k<64;k++){
    float xv = g3[g*64+k];
    a0 = fmaf(xv, Wv[k], a0);
    a1 = fmaf(xv, We[k], a1);
    a2 = fmaf(xv, Wd[k], a2);
    a3 = fmaf(xv, Wh[k], a3);
  }
  out[g] = a0; out[NG+g] = a1; out[2*NG+g] = a2; out[3*NG+g] = a3;
}

extern "C" void kernel_launch(void* const* d_in, const int* in_sizes, int n_in,
                              void* d_out, int out_size, void* d_ws, size_t ws_size,
                              hipStream_t stream)
{
  const float* x         = (const float*)d_in[0];
  const float* edge_attr = (const float*)d_in[1];
  const int*   ei        = (const int*)d_in[2];
  const int*   batch     = (const int*)d_in[3];
  const float* W_node    = (const float*)d_in[4];
  const float* b_node    = (const float*)d_in[5];
  const float* W_edge    = (const float*)d_in[6];
  const float* b_edge    = (const float*)d_in[7];
  const float* Wf        = (const float*)d_in[8];
  const float* bf        = (const float*)d_in[9];
  const float* Ws        = (const float*)d_in[10];
  const float* bs        = (const float*)d_in[11];
  const float* bn_g      = (const float*)d_in[12];
  const float* bn_b      = (const float*)d_in[13];
  const float* bn_m      = (const float*)d_in[14];
  const float* bn_v      = (const float*)d_in[15];
  const float* W1        = (const float*)d_in[16];
  const float* b1        = (const float*)d_in[17];
  const float* bn1_g     = (const float*)d_in[18];
  const float* bn1_b     = (const float*)d_in[19];
  const float* bn1_m     = (const float*)d_in[20];
  const float* bn1_v     = (const float*)d_in[21];
  const float* W2        = (const float*)d_in[22];
  const float* b2        = (const float*)d_in[23];
  const float* bn2_g     = (const float*)d_in[24];
  const float* bn2_b     = (const float*)d_in[25];
  const float* bn2_m     = (const float*)d_in[26];
  const float* bn2_v     = (const float*)d_in[27];
  const float* W3        = (const float*)d_in[28];
  const float* b3        = (const float*)d_in[29];
  const float* Wv        = (const float*)d_in[30];
  const float* bv        = (const float*)d_in[31];
  const float* W_en      = (const float*)d_in[32];
  const float* b_en      = (const float*)d_in[33];
  const float* Wd        = (const float*)d_in[34];
  const float* bd        = (const float*)d_in[35];
  const float* Wh        = (const float*)d_in[36];
  const float* bh        = (const float*)d_in[37];

  float* wsf  = (float*)d_ws;
  float* h    = wsf;                          // 2,560,000
  float* hacc = wsf + 2560000;                // 2,560,000
  float* Pd   = wsf + 5120000;                // 5,120,000 (float2/elem)
  float* Ps   = wsf + 10240000;               // 5,120,000
  unsigned short* Wpk_hi = (unsigned short*)(wsf + 15360000); // 983,040 shorts
  unsigned short* Wpk_md = (unsigned short*)(wsf + 15851520); // 983,040 shorts
  unsigned short* Wpk_lo = (unsigned short*)(wsf + 16343040); // 983,040 shorts
  float* psum = wsf + 16834560;               // 32768
  float* pmax = psum + 32768;                 // 32768
  float* pcnt = pmax + 32768;                 // 256
  float* g1   = pcnt + 256;                   // 65536
  float* g2   = g1 + 65536;                   // 32768
  float* g3   = g2 + 32768;                   // 16384
  int*   deg  = (int*)(wsf + 16982272);       // 20000
  int*   start= deg + 20000;                  // 20000
  int*   cur  = start + 20000;                // 20000
  int2*  esd  = (int2*)(cur + 20000);         // 160000 int2 = 320000 ints
  float* ea_s = (float*)(cur + 20000 + 320000); // 480000

  // one-time: dst-sort
  hipMemsetAsync(deg, 0, 20000*sizeof(int), stream);
  k_hist<<<(NE+255)/256, 256, 0, stream>>>(ei, deg);
  k_scan<<<1, 1024, 0, stream>>>(deg, start, cur);
  k_scatter<<<(NE+255)/256, 256, 0, stream>>>(ei, edge_attr, cur, esd, ea_s);

  k_pack_w<<<480, 256, 0, stream>>>(Wf, Ws, Wpk_hi, Wpk_md, Wpk_lo);
  k_embed_node<<<(NN*128+255)/256, 256, 0, stream>>>(x, W_node, b_node, h, hacc);
  hipMemsetAsync(psum, 0, (size_t)(32768+32768+256)*sizeof(float), stream);

  for (int i=0;i<10;i++){
    const unsigned short* WH = Wpk_hi + (size_t)i*6*16384;
    const unsigned short* WM = Wpk_md + (size_t)i*6*16384;
    const unsigned short* WL = Wpk_lo + (size_t)i*6*16384;
    k_nodeproj_mfma<<<314, 512, 0, stream>>>(h, WH, WM, WL,
        bf + i*128, bs + i*128, Pd, Ps);
    k_edge_mfma<<<4*NQB, 256, 0, stream>>>(ea_s, W_edge, b_edge,
        WH, WM, esd, Pd, Ps, hacc);
    if (i < 9)
      k_bn<<<(NN*32+255)/256, 256, 0, stream>>>(hacc, h,
          bn_g + i*128, bn_b + i*128, bn_m + i*128, bn_v + i*128, h, hacc, i&1);
    else
      k_bn_pool<<<(NN*128+255)/256, 256, 0, stream>>>(hacc, h,
          bn_g + i*128, bn_b + i*128, bn_m + i*128, bn_v + i*128,
          batch, psum, pmax, pcnt, i&1);
  }

  k_mlp1<<<(NG*256)/256, 256, 0, stream>>>(psum, pmax, pcnt, W1, b1, bn1_g, bn1_b, bn1_m, bn1_v, g1);
  k_mlp2<<<(NG*128)/256, 256, 0, stream>>>(g1, W2, b2, bn2_g, bn2_b, bn2_m, bn2_v, g2);
  k_mlp3<<<(NG*64)/256, 256, 0, stream>>>(g2, W3, b3, g3);
  k_heads<<<1, 256, 0, stream>>>(g3, Wv, bv, W_en, b_en, Wd, bd, Wh, bh, (float*)d_out);
}